// Round 6
// baseline (224.048 us; speedup 1.0000x reference)
//
#include <hip/hip_runtime.h>
#include <hip/hip_bf16.h>
#include <stdint.h>

typedef unsigned short u16;
typedef __attribute__((ext_vector_type(8))) short short8;
typedef __attribute__((ext_vector_type(16))) float f32x16;

#define B_DIM 4096
#define D_DIM 1024
#define H_DIM 1024
#define K_DIM 2048   // D + H
#define N_DIM 4096   // 4H
#define LN_EPS 1e-5f

// ---------- helpers ----------
__device__ __forceinline__ u16 f2bf(float f) {
    union { float f; uint32_t u; } v; v.f = f;
    uint32_t u = v.u;
    uint32_t r = (u + 0x7FFFu + ((u >> 16) & 1u)) >> 16;  // RNE
    return (u16)r;
}
__device__ __forceinline__ float bf2f(u16 h) {
    union { uint32_t u; float f; } v; v.u = ((uint32_t)h) << 16;
    return v.f;
}
__device__ __forceinline__ void gld16(const u16* g, u16* l) {
    __builtin_amdgcn_global_load_lds(
        (const __attribute__((address_space(1))) void*)g,
        (__attribute__((address_space(3))) void*)l,
        16, 0, 0);
}
__device__ __forceinline__ float sigm(float x) { return 1.0f / (1.0f + __expf(-x)); }
__device__ __forceinline__ float tanh_fast(float x) { return 1.0f - 2.0f / (__expf(2.0f * x) + 1.0f); }

// ---------- kernel 1: fused prep ----------
__global__ __launch_bounds__(256) void prep(const float* __restrict__ x,
                                            const float* __restrict__ h,
                                            const float* __restrict__ Wx,
                                            const float* __restrict__ Wh,
                                            u16* __restrict__ A,
                                            u16* __restrict__ Bt) {
    __shared__ u16 tile[64 * 64];
    const int t = threadIdx.x;
    if (blockIdx.x < 4096) {
        int id = blockIdx.x * 256 + t;
        int row = id >> 8;
        int col = (id & 255) * 8;
        const float* src = (col < D_DIM) ? (x + (size_t)row * D_DIM + col)
                                         : (h + (size_t)row * H_DIM + (col - D_DIM));
        float4 v0 = ((const float4*)src)[0];
        float4 v1 = ((const float4*)src)[1];
        union { u16 us[8]; uint4 u; } p;
        p.us[0] = f2bf(v0.x); p.us[1] = f2bf(v0.y); p.us[2] = f2bf(v0.z); p.us[3] = f2bf(v0.w);
        p.us[4] = f2bf(v1.x); p.us[5] = f2bf(v1.y); p.us[6] = f2bf(v1.z); p.us[7] = f2bf(v1.w);
        *(uint4*)(A + (size_t)id * 8) = p.u;
    } else {
        const int v = blockIdx.x - 4096;       // 0..2047 = 64 x 32
        const int n0 = (v & 63) * 64;
        const int k0 = (v >> 6) * 64;
        const int kl  = t >> 4;                // 0..15
        const int nl4 = (t & 15) * 4;          // 0..60
#pragma unroll
        for (int it = 0; it < 4; ++it) {
            const int klocal = kl + it * 16;
            const int k = k0 + klocal;
            const float* src = (k < D_DIM) ? (Wx + (size_t)k * N_DIM)
                                           : (Wh + (size_t)(k - D_DIM) * N_DIM);
            float4 w = *(const float4*)(src + n0 + nl4);
            union { u16 us[4]; uint2 u; } p;
            p.us[0] = f2bf(w.x); p.us[1] = f2bf(w.y); p.us[2] = f2bf(w.z); p.us[3] = f2bf(w.w);
            const int swz = 8 * ((klocal >> 4) & 3);
            *(uint2*)(tile + klocal * 64 + (nl4 ^ swz)) = p.u;
        }
        __syncthreads();
        const int nl = t >> 2;
        const int kp = (t & 3) * 16;
        const int swz = 8 * (t & 3);
        union { u16 us[16]; uint4 q[2]; } o;
#pragma unroll
        for (int i = 0; i < 16; ++i)
            o.us[i] = tile[(kp + i) * 64 + (nl ^ swz)];
        u16* dst = Bt + (size_t)(n0 + nl) * K_DIM + k0 + kp;
        *(uint4*)dst = o.q[0];
        *(uint4*)(dst + 8) = o.q[1];
    }
}

// ---------- kernel 2: GEMM a = A @ Bt^T + bias -> bf16 [4096][4096] ----------
// 256x256 block, 4 waves, 128x128 per wave (4x4 of 32x32x16), BK=64, LDS dbuf,
// and (new this round) REGISTER-LEVEL kk-pipelining: fragments for kk+1 are
// ds_read while kk's 16 MFMAs execute, so at 1 wave/SIMD the ~120cyc LDS
// latency is hidden by the ~128cyc MFMA shadow instead of (absent) TLP.
__global__ __launch_bounds__(256, 1) void gemm_bf16(const u16* __restrict__ A,   // [4096][2048]
                                                    const u16* __restrict__ Bt,  // [4096][2048]
                                                    const float* __restrict__ bias,
                                                    u16* __restrict__ C) {       // [4096][4096]
    __shared__ u16 As[2][16384];   // [buf][hp*8192 + row*32 + s*8]
    __shared__ u16 Bs[2][16384];
    const int tid = threadIdx.x;
    const int wave = tid >> 6, lane = tid & 63;
    const int m0 = blockIdx.y * 256;
    const int n0 = blockIdx.x * 256;
    const int wm = (wave & 1) * 128;
    const int wn = (wave >> 1) * 128;

    f32x16 acc[4][4] = {};

    // staging: chunk = 1 KB = 16 rows x 32 u16. Per matrix 32 chunks (hp,c),
    // wave handles ch = wave*8+q: hp = ch>>4, c = ch&15. lane l -> row c*16+(l>>2);
    // stored block l&3 holds global block perm = ((l&3) - (l>>3)) & 3
    const int perm = ((lane & 3) - (lane >> 3)) & 3;
    const int vofs = (lane >> 2) * K_DIM + perm * 8;   // per-lane global offset
    const int lr = lane & 31, half = lane >> 5;

    // fragment double-buffer in VGPRs (2 sets of 4 A + 4 B short8)
    short8 aF[2][4], bF[2][4];

#define READ_FRAGS(set, cb, kk)                                                  \
    {                                                                            \
        const int hp_ = (kk) >> 1;                                               \
        const int s_ = ((((kk) & 1) * 2 + half) + (lr >> 1)) & 3;                \
        const int ko_ = hp_ * 8192 + s_ * 8;                                     \
        _Pragma("unroll")                                                        \
        for (int i_ = 0; i_ < 4; ++i_)                                           \
            aF[set][i_] = *(const short8*)(&As[cb][ko_ + (wm + i_ * 32 + lr) * 32]); \
        _Pragma("unroll")                                                        \
        for (int j_ = 0; j_ < 4; ++j_)                                           \
            bF[set][j_] = *(const short8*)(&Bs[cb][ko_ + (wn + j_ * 32 + lr) * 32]); \
    }

    for (int it = 0; it < K_DIM / 64 + 1; ++it) {
        if (it < K_DIM / 64) {
            const int kt = it * 64;
            const int buf = it & 1;
#pragma unroll
            for (int q = 0; q < 8; ++q) {
                const int ch = wave * 8 + q;
                const int hp = ch >> 4, c = ch & 15;
                const int so = (c * 16) * K_DIM + kt + hp * 32;   // wave-uniform
                const int ldso = hp * 8192 + c * 512;
                gld16(A  + (size_t)m0 * K_DIM + so + vofs, &As[buf][ldso]);
                gld16(Bt + (size_t)n0 * K_DIM + so + vofs, &Bs[buf][ldso]);
            }
        }
        if (it == 0) { __syncthreads(); continue; }

        const int cbuf = (it - 1) & 1;
        READ_FRAGS(0, cbuf, 0);
#pragma unroll
        for (int kk = 0; kk < 4; ++kk) {
            const int cur = kk & 1;
            if (kk < 3) READ_FRAGS(cur ^ 1, cbuf, kk + 1);   // prefetch next frags
#pragma unroll
            for (int i = 0; i < 4; ++i)
#pragma unroll
                for (int j = 0; j < 4; ++j)
                    acc[i][j] = __builtin_amdgcn_mfma_f32_32x32x16_bf16(aF[cur][i], bF[cur][j], acc[i][j], 0, 0, 0);
        }
        __syncthreads();   // prefetch for `it` drains here, after full compute phase
    }
#undef READ_FRAGS

    // epilogue: 32x32 C/D layout col=lane&31, row=(reg&3)+8*(reg>>2)+4*(lane>>5)
#pragma unroll
    for (int i = 0; i < 4; ++i) {
#pragma unroll
        for (int j = 0; j < 4; ++j) {
            const int c = n0 + wn + 32 * j + lr;
            const float bb = bias[c];
#pragma unroll
            for (int reg = 0; reg < 16; ++reg) {
                const int row = m0 + wm + 32 * i + (reg & 3) + 8 * (reg >> 2) + 4 * half;
                C[(size_t)row * N_DIM + c] = f2bf(acc[i][j][reg] + bb);
            }
        }
    }
}

// ---------- kernel 3: LayerNorm + gates + cell update (single pass over aT) ----------
__global__ __launch_bounds__(256) void ln_lstm(const u16* __restrict__ aT,     // [4096][4096] bf16
                                               const float* __restrict__ pc,   // prev_c
                                               const float* __restrict__ gamma,
                                               const float* __restrict__ beta,
                                               float* __restrict__ out) {      // [h | c]
    const int row = blockIdx.x;
    const int t = threadIdx.x;
    const u16* ar = aT + (size_t)row * N_DIM;
    const int j0 = t * 4;

    union U2 { uint2 u; u16 us[4]; };
    U2 g4[4];
#pragma unroll
    for (int s = 0; s < 4; ++s) g4[s].u = *(const uint2*)(ar + s * H_DIM + j0);

    float sum = 0.f, ssq = 0.f;
#pragma unroll
    for (int s = 0; s < 4; ++s)
#pragma unroll
        for (int e = 0; e < 4; ++e) { float v = bf2f(g4[s].us[e]); sum += v; ssq += v * v; }

#pragma unroll
    for (int off = 32; off > 0; off >>= 1) {
        sum += __shfl_down(sum, off, 64);
        ssq += __shfl_down(ssq, off, 64);
    }
    __shared__ float red[8];
    if ((t & 63) == 0) { red[t >> 6] = sum; red[4 + (t >> 6)] = ssq; }
    __syncthreads();
    const float ts = red[0] + red[1] + red[2] + red[3];
    const float tq = red[4] + red[5] + red[6] + red[7];
    const float mu = ts * (1.0f / N_DIM);
    const float var = fmaxf(tq * (1.0f / N_DIM) - mu * mu, 0.0f);
    const float rs = rsqrtf(var + LN_EPS);

    float vi[4], vf[4], vo[4], vg[4];
    auto gate = [&](int s, float* v) {
        const int off = s * H_DIM;
        float4 gm = *(const float4*)(gamma + off + j0);
        float4 bt = *(const float4*)(beta + off + j0);
        v[0] = (bf2f(g4[s].us[0]) - mu) * rs * gm.x + bt.x;
        v[1] = (bf2f(g4[s].us[1]) - mu) * rs * gm.y + bt.y;
        v[2] = (bf2f(g4[s].us[2]) - mu) * rs * gm.z + bt.z;
        v[3] = (bf2f(g4[s].us[3]) - mu) * rs * gm.w + bt.w;
    };
    gate(0, vi); gate(1, vf); gate(2, vo); gate(3, vg);

    float4 c4 = *(const float4*)(pc + (size_t)row * H_DIM + j0);
    float cin[4] = {c4.x, c4.y, c4.z, c4.w};
    float nh[4], nc[4];
#pragma unroll
    for (int r = 0; r < 4; ++r) {
        float ig = sigm(vi[r]);
        float fg = sigm(vf[r]);
        float og = sigm(vo[r]);
        float gg = tanh_fast(vg[r]);
        nc[r] = fg * cin[r] + ig * gg;
        nh[r] = og * tanh_fast(nc[r]);
    }
    float4 h4 = {nh[0], nh[1], nh[2], nh[3]};
    float4 c4o = {nc[0], nc[1], nc[2], nc[3]};
    *(float4*)(out + (size_t)row * H_DIM + j0) = h4;
    *(float4*)(out + (size_t)B_DIM * H_DIM + (size_t)row * H_DIM + j0) = c4o;
}

// ---------- launch ----------
extern "C" void kernel_launch(void* const* d_in, const int* in_sizes, int n_in,
                              void* d_out, int out_size, void* d_ws, size_t ws_size,
                              hipStream_t stream) {
    const float* x  = (const float*)d_in[0];
    const float* ph = (const float*)d_in[1];
    const float* pc = (const float*)d_in[2];
    const float* Wx = (const float*)d_in[3];
    const float* Wh = (const float*)d_in[4];
    const float* b  = (const float*)d_in[5];
    const float* gm = (const float*)d_in[6];
    const float* bt = (const float*)d_in[7];
    float* out = (float*)d_out;

    char* ws = (char*)d_ws;
    u16* Abf = (u16*)ws;                               // 16 MiB: [4096][2048] bf16
    u16* Btb = (u16*)(ws + (size_t)16 * 1024 * 1024);  // 16 MiB: [4096][2048] bf16
    u16* aT  = (u16*)(ws + (size_t)32 * 1024 * 1024);  // 32 MiB: [4096][4096] bf16

    prep<<<dim3(4096 + 2048), dim3(256), 0, stream>>>(x, ph, Wx, Wh, Abf, Btb);
    gemm_bf16<<<dim3(16, 16), dim3(256), 0, stream>>>(Abf, Btb, b, aT);
    ln_lstm<<<dim3(4096), dim3(256), 0, stream>>>(aT, pc, gm, bt, out);
}